// Round 1
// baseline (9.673 us; speedup 1.0000x reference)
//
#include <hip/hip_runtime.h>
#include <math.h>

// AUROC pairwise-hinge surrogate loss, N = 16384.
//
// Algebraic collapse: s = sigmoid(y_pred) in (0,1)  =>  s_p - s_n in (-1,1)
// =>  1 - (s_p - s_n) in (0,2)  =>  relu(1 - diff) == 1 - diff for EVERY
// (pos, neg) pair (equality also holds at the f32 boundary s_p=1, s_n=0
// where 1 - diff == 0). Hence
//   total = sum_{p,n} (1 - s_p + s_n) = P*Q - Q*Sp + P*Sn
// with Sp = sum of s over positives, Sn = sum over negatives.
// The O(N^2) pairwise sum becomes one O(N) reduction.

__global__ __launch_bounds__(1024)
void auroc_reduce(const float* __restrict__ yp,
                  const int*   __restrict__ yt,
                  float*       __restrict__ out,
                  int n)
{
    const int tid = threadIdx.x;

    float sp = 0.0f, sn = 0.0f;   // sum of sigmoid over pos / neg
    int   cp = 0,    cq = 0;      // counts of pos / neg

    // Vectorized main loop: float4 / int4, lane-contiguous (coalesced).
    const int n4 = n >> 2;
    const float4* __restrict__ yp4 = (const float4*)yp;
    const int4*   __restrict__ yt4 = (const int4*)yt;
    for (int i = tid; i < n4; i += 1024) {
        float4 x = yp4[i];
        int4   t = yt4[i];
        float s;
        s = 1.0f / (1.0f + __expf(-x.x)); if (t.x == 1) { sp += s; ++cp; } else if (t.x == 0) { sn += s; ++cq; }
        s = 1.0f / (1.0f + __expf(-x.y)); if (t.y == 1) { sp += s; ++cp; } else if (t.y == 0) { sn += s; ++cq; }
        s = 1.0f / (1.0f + __expf(-x.z)); if (t.z == 1) { sp += s; ++cp; } else if (t.z == 0) { sn += s; ++cq; }
        s = 1.0f / (1.0f + __expf(-x.w)); if (t.w == 1) { sp += s; ++cp; } else if (t.w == 0) { sn += s; ++cq; }
    }
    // Scalar tail (n % 4 != 0 safety; no-op for N = 16384).
    for (int i = (n4 << 2) + tid; i < n; i += 1024) {
        float s = 1.0f / (1.0f + __expf(-yp[i]));
        int t = yt[i];
        if (t == 1) { sp += s; ++cp; } else if (t == 0) { sn += s; ++cq; }
    }

    float fp = (float)cp, fq = (float)cq;

    // Wave-level butterfly reduction (wave = 64 lanes on CDNA).
    #pragma unroll
    for (int off = 32; off > 0; off >>= 1) {
        sp += __shfl_down(sp, off);
        sn += __shfl_down(sn, off);
        fp += __shfl_down(fp, off);
        fq += __shfl_down(fq, off);
    }

    // Cross-wave reduction through LDS (16 waves in a 1024-thread block).
    __shared__ float red[16][4];
    const int wave = tid >> 6;
    const int lane = tid & 63;
    if (lane == 0) {
        red[wave][0] = sp;
        red[wave][1] = sn;
        red[wave][2] = fp;
        red[wave][3] = fq;
    }
    __syncthreads();

    if (tid == 0) {
        float tsp = 0.0f, tsn = 0.0f, tp = 0.0f, tq = 0.0f;
        #pragma unroll
        for (int w = 0; w < 16; ++w) {
            tsp += red[w][0];
            tsn += red[w][1];
            tp  += red[w][2];
            tq  += red[w][3];
        }
        float denom = tp * tq;
        float total = tp * tq - tq * tsp + tp * tsn;
        out[0] = (denom > 0.0f) ? (total / fmaxf(denom, 1.0f)) : 0.0f;
    }
}

extern "C" void kernel_launch(void* const* d_in, const int* in_sizes, int n_in,
                              void* d_out, int out_size, void* d_ws, size_t ws_size,
                              hipStream_t stream) {
    const float* y_pred = (const float*)d_in[0];
    const int*   y_true = (const int*)d_in[1];
    float* out = (float*)d_out;
    const int n = in_sizes[0];   // 16384

    auroc_reduce<<<1, 1024, 0, stream>>>(y_pred, y_true, out, n);
}